// Round 4
// baseline (293.662 us; speedup 1.0000x reference)
//
#include <hip/hip_runtime.h>
#include <math.h>

#define KK      7
#define C1      21
#define NPLANES (KK * KK * C1)   // 1029
#define H       100
#define W       100
#define TS      101              // padded LDS row stride: bank stride 5 (coprime 32)
#define NCHUNK  ((H * W) / 4)    // 2500 float4 chunks per plane
#define PREFK   10               // ceil(2500 / 256)

// ---------------------------------------------------------------------------
// INSTRUMENTED ROUND: kernel bodies are the proven round-0 version (213.8us).
// The launcher runs plane_partial 5x (idempotent: same deterministic write to
// partial[] each time) + reduce_softmax 1x.  Purpose: back out plane_partial's
// true duration, which has never appeared in the top-5 counters:
//     P = (dur_this_round - 215) / 4   (+-0.7us)
// Output is bit-identical to a single run (absmax stays 0.0).
// ---------------------------------------------------------------------------
__global__ __launch_bounds__(256) void plane_partial(
    const float* __restrict__ src,   // full cls_conv_out
    size_t batch_off,                // offset of last batch element (elements)
    const int*  __restrict__ rois,   // [nrois][4] = ymin,xmin,ymax,xmax
    int nrois,
    float* __restrict__ partial)     // [NPLANES][nrois]
{
    const int t  = threadIdx.x;
    const int p0 = blockIdx.x * 2;
    const int p1 = p0 + 1;
    const bool has_p1 = (p1 < NPLANES);

    __shared__ float tile[H * TS];   // 40400 B

    // ---- stage plane 0 (float4 global -> scalar padded LDS) ----
    {
        const float4* p4 = (const float4*)(src + batch_off + (size_t)p0 * (H * W));
        #pragma unroll
        for (int k = 0; k < PREFK; ++k) {
            int i = t + 256 * k;
            if (i < NCHUNK) {
                float4 v = p4[i];
                int g = i * 4;
                int y = g / W, x = g - y * W;        // rows don't split (100%4==0)
                float* d = &tile[y * TS + x];
                d[0] = v.x; d[1] = v.y; d[2] = v.z; d[3] = v.w;
            }
        }
    }
    __syncthreads();

    // ---- issue prefetch of plane 1 into registers (loads stay in flight) ----
    float4 pref[PREFK];
    if (has_p1) {
        const float4* p4 = (const float4*)(src + batch_off + (size_t)p1 * (H * W));
        #pragma unroll
        for (int k = 0; k < PREFK; ++k) {
            int i = t + 256 * k;
            if (i < NCHUNK) pref[k] = p4[i];
        }
    }

    for (int pass = 0; pass < 2; ++pass) {
        const int p = p0 + pass;
        if (p >= NPLANES) break;
        const int jl = p / C1;
        const int l  = jl % KK;
        const int j  = jl / KK;

        if (pass == 1) {
            // overwrite tile with the prefetched plane
            __syncthreads();          // all pass-0 tile reads done
            #pragma unroll
            for (int k = 0; k < PREFK; ++k) {
                int i = t + 256 * k;
                if (i < NCHUNK) {
                    float4 v = pref[k];
                    int g = i * 4;
                    int y = g / W, x = g - y * W;
                    float* d = &tile[y * TS + x];
                    d[0] = v.x; d[1] = v.y; d[2] = v.z; d[3] = v.w;
                }
            }
            __syncthreads();
        }

        // row-prefix: thread y scans row y.  bank(t,x) = (5t + x) & 31:
        // distinct across 32 lanes, 2 lanes/bank across wave64 -> free.
        if (t < H) {
            float s = 0.f;
            float* row = &tile[t * TS];
            for (int x = 0; x < W; ++x) { s += row[x]; row[x] = s; }
        }
        __syncthreads();

        // col-prefix: thread x scans column x (lane-consecutive banks, free)
        if (t < W) {
            float s = 0.f;
            for (int y = 0; y < H; ++y) { s += tile[y * TS + t]; tile[y * TS + t] = s; }
        }
        __syncthreads();

        // ROI lookups.  Inclusive integral I[y][x] = sum_{y'<=y, x'<=x}.
        // rect rows [y0, y0+ys), cols [x0, x0+xs):
        // S = I[y1][x1] - I[y0-1][x1] - I[y1][x0-1] + I[y0-1][x0-1]
        float* prow = partial + (size_t)p * nrois;
        for (int n = t; n < nrois; n += 256) {
            const int4 r  = ((const int4*)rois)[n];   // ymin,xmin,ymax,xmax
            const int ys  = (r.z - r.x) / KK;
            const int xs  = (r.w - r.y) / KK;
            const int y0  = r.x + j * ys;
            const int x0  = r.y + l * xs;
            const int y1  = y0 + ys - 1;              // <= 94 < 100
            const int x1  = x0 + xs - 1;

            float S = tile[y1 * TS + x1];
            if (x0 > 0)           S -= tile[y1 * TS + (x0 - 1)];
            if (y0 > 0)           S -= tile[(y0 - 1) * TS + x1];
            if (y0 > 0 && x0 > 0) S += tile[(y0 - 1) * TS + (x0 - 1)];

            prow[n] = S;                              // coalesced 4B store
        }
    }
}

// ---------------------------------------------------------------------------
// Stage 2 (fused reduce + softmax): block handles RB=16 ROIs.
// ---------------------------------------------------------------------------
#define RB 16

__global__ __launch_bounds__(256) void reduce_softmax(
    const float* __restrict__ partial,   // [NPLANES][nrois]
    const int*   __restrict__ rois,
    int nrois,
    float*       __restrict__ out)
{
    const int dn = threadIdx.x & (RB - 1);
    const int cg = threadIdx.x / RB;     // 0..15
    const int n  = blockIdx.x * RB + dn;

    __shared__ float ch[RB][C1];

    if (n < nrois) {
        for (int c = cg; c < C1; c += 16) {
            float s = 0.f;
            const float* pc = partial + (size_t)c * nrois + n;
            #pragma unroll
            for (int jl = 0; jl < KK * KK; ++jl) {
                s += pc[(size_t)jl * C1 * nrois];
            }
            ch[dn][c] = s;
        }
    }
    __syncthreads();

    if (threadIdx.x < RB) {
        const int n2 = blockIdx.x * RB + threadIdx.x;
        if (n2 < nrois) {
            const int4 r  = ((const int4*)rois)[n2];
            const int ys  = (r.z - r.x) / KK;
            const int xs  = (r.w - r.y) / KK;
            const float inv = 1.0f / (49.0f * (float)(ys * xs));

            float v[C1];
            float m = -INFINITY;
            #pragma unroll
            for (int c = 0; c < C1; ++c) {
                v[c] = ch[threadIdx.x][c] * inv;
                m = fmaxf(m, v[c]);
            }
            float s = 0.f;
            #pragma unroll
            for (int c = 0; c < C1; ++c) { v[c] = __expf(v[c] - m); s += v[c]; }
            const float rs = 1.0f / s;
            #pragma unroll
            for (int c = 0; c < C1; ++c) out[(size_t)n2 * C1 + c] = v[c] * rs;
        }
    }
}

// ---------------------------------------------------------------------------
// Fallback (ws too small): direct rectangle summation from global.
// ---------------------------------------------------------------------------
__global__ __launch_bounds__(256) void roi_pool_direct(
    const float* __restrict__ src,
    size_t batch_off,
    const int*   __restrict__ rois,
    float*       __restrict__ out)
{
    const int n = blockIdx.x;
    const int t = threadIdx.x;

    __shared__ float chsum[C1];
    if (t < C1) chsum[t] = 0.f;
    __syncthreads();

    const int ymin = rois[4 * n + 0];
    const int xmin = rois[4 * n + 1];
    const int ymax = rois[4 * n + 2];
    const int xmax = rois[4 * n + 3];
    const int ys = (ymax - ymin) / KK;
    const int xs = (xmax - xmin) / KK;

    const float* base = src + batch_off;

    for (int idx = t; idx < NPLANES; idx += blockDim.x) {
        const int c  = idx % C1;
        const int jl = idx / C1;
        const int l  = jl % KK;
        const int j  = jl / KK;
        const int y0 = ymin + j * ys;
        const int x0 = xmin + l * xs;
        const float* plane = base + (size_t)idx * (H * W);
        float s = 0.f;
        for (int y = y0; y < y0 + ys; ++y) {
            const float* row = plane + (size_t)y * W + x0;
            for (int x = 0; x < xs; ++x) s += row[x];
        }
        atomicAdd(&chsum[c], s);
    }
    __syncthreads();

    if (t == 0) {
        const float inv = 1.0f / (49.0f * (float)(ys * xs));
        float m = -INFINITY;
        float v[C1];
        for (int c = 0; c < C1; ++c) { v[c] = chsum[c] * inv; m = fmaxf(m, v[c]); }
        float s = 0.f;
        for (int c = 0; c < C1; ++c) { v[c] = expf(v[c] - m); s += v[c]; }
        const float rs = 1.0f / s;
        for (int c = 0; c < C1; ++c) out[(size_t)n * C1 + c] = v[c] * rs;
    }
}

extern "C" void kernel_launch(void* const* d_in, const int* in_sizes, int n_in,
                              void* d_out, int out_size, void* d_ws, size_t ws_size,
                              hipStream_t stream)
{
    const float* cls  = (const float*)d_in[0];
    const int*   rois = (const int*)d_in[1];
    float*       out  = (float*)d_out;

    const int nrois = in_sizes[1] / 4;                         // 2000
    const size_t plane_elems = (size_t)NPLANES * H * W;        // 10.29 M
    const int B = (int)((size_t)in_sizes[0] / plane_elems);    // 4
    const size_t batch_off = (size_t)(B - 1) * plane_elems;

    const size_t need = (size_t)NPLANES * nrois * sizeof(float);  // ~8.2 MB
    if (ws_size >= need) {
        float* partial = (float*)d_ws;
        const int nblocks = (NPLANES + 1) / 2;                 // 515
        // MEASUREMENT: 5 idempotent repetitions of the plane kernel.
        // P = (dur - 215) / 4.  Output unchanged vs a single run.
        for (int rep = 0; rep < 5; ++rep) {
            plane_partial<<<nblocks, 256, 0, stream>>>(cls, batch_off, rois, nrois, partial);
        }
        reduce_softmax<<<(nrois + RB - 1) / RB, 256, 0, stream>>>(partial, rois, nrois, out);
    } else {
        roi_pool_direct<<<nrois, 256, 0, stream>>>(cls, batch_off, rois, out);
    }
}

// Round 6
// 222.732 us; speedup vs baseline: 1.3185x; 1.3185x over previous
//
#include <hip/hip_runtime.h>
#include <math.h>

#define KK      7
#define C1      21
#define NPLANES (KK * KK * C1)   // 1029
#define H       100
#define W       100
#define TS      100              // FLAT tile: tile == plane, 16B-aligned rows
#define NCHUNK  ((H * W) / 4)    // 2500 float4 chunks per plane
#define PREFK   10               // ceil(2500 / 256)

// ---------------------------------------------------------------------------
// Round-6 = round-5 resubmit (round-5 failed on container acquisition, not on
// the kernel).  Attack LDS *instruction count* (round-4 measurement:
// plane_partial = 19.6us warm = 4.8us CU-time/plane, work-throughput-bound;
// rounds 2/3 restructured latency at constant op count -> nulls).
//  - TS=100 flat tile: staging is a single ds_write_b128 per float4 lane,
//    no y/x div/mod VALU at all.
//  - row scan b128: 25x {read_b128, in-quad prefix, +carry, write_b128}
//    = 100 wave-instrs vs 400 b32.  (scalar b32 at stride 100 would be
//    8-way conflicted -- b128 required.)
//  - col scan b128: 25 threads x 4 columns, acc += v per row: 200 short
//    instrs vs 400 b32; per-column summation order unchanged.
//  - ROI phase identical to round-0 (proven).
// Only change vs round-5 source: tile declared as __align__(16) float[] and
// cast to float4* (conservative aliasing direction); codegen identical.
// ---------------------------------------------------------------------------
__global__ __launch_bounds__(256) void plane_partial(
    const float* __restrict__ src,   // full cls_conv_out
    size_t batch_off,                // offset of last batch element (elements)
    const int*  __restrict__ rois,   // [nrois][4] = ymin,xmin,ymax,xmax
    int nrois,
    float* __restrict__ partial)     // [NPLANES][nrois]
{
    const int t  = threadIdx.x;
    const int p0 = blockIdx.x * 2;
    const int p1 = p0 + 1;
    const bool has_p1 = (p1 < NPLANES);

    __shared__ __align__(16) float tile[H * TS];   // 40,000 B, 16B aligned
    float4* tile4 = (float4*)tile;

    // ---- stage plane 0: float4 global -> float4 LDS, 1 instr per chunk ----
    {
        const float4* p4 = (const float4*)(src + batch_off + (size_t)p0 * (H * W));
        #pragma unroll
        for (int k = 0; k < PREFK; ++k) {
            int i = t + 256 * k;
            if (i < NCHUNK) tile4[i] = p4[i];
        }
    }
    __syncthreads();

    // ---- issue prefetch of plane 1 into registers (loads stay in flight) ----
    float4 pref[PREFK];
    if (has_p1) {
        const float4* p4 = (const float4*)(src + batch_off + (size_t)p1 * (H * W));
        #pragma unroll
        for (int k = 0; k < PREFK; ++k) {
            int i = t + 256 * k;
            if (i < NCHUNK) pref[k] = p4[i];
        }
    }

    for (int pass = 0; pass < 2; ++pass) {
        const int p = p0 + pass;
        if (p >= NPLANES) break;
        const int jl = p / C1;
        const int l  = jl % KK;
        const int j  = jl / KK;

        if (pass == 1) {
            __syncthreads();          // all pass-0 tile reads done
            #pragma unroll
            for (int k = 0; k < PREFK; ++k) {
                int i = t + 256 * k;
                if (i < NCHUNK) tile4[i] = pref[k];
            }
            __syncthreads();
        }

        // ---- row-prefix, b128: thread r scans row r in 25 quads.
        // In-quad prefix keeps the sequential association: v.y=a+b,
        // v.z=(a+b)+c, v.w=((a+b)+c)+d; then +carry.
        if (t < H) {
            float4* row = (float4*)&tile[t * TS];   // row base 400t B, 16B ok
            float s = 0.f;
            #pragma unroll
            for (int k = 0; k < W / 4; ++k) {
                float4 v = row[k];
                v.y += v.x; v.z += v.y; v.w += v.z;
                v.x += s; v.y += s; v.z += s; v.w += s;
                s = v.w;
                row[k] = v;
            }
        }
        __syncthreads();

        // ---- col-prefix, b128: thread c (<25) owns columns 4c..4c+3;
        // element-wise running sum down the rows (order per column unchanged).
        if (t < W / 4) {
            float4* col = (float4*)&tile[t * 4];    // stride 25 float4 per row
            float4 s = make_float4(0.f, 0.f, 0.f, 0.f);
            #pragma unroll 10
            for (int y = 0; y < H; ++y) {
                float4 v = col[y * (TS / 4)];
                s.x += v.x; s.y += v.y; s.z += v.z; s.w += v.w;
                col[y * (TS / 4)] = s;
            }
        }
        __syncthreads();

        // ---- ROI lookups (round-0 form, proven).
        // I[y][x] inclusive integral; rect rows [y0,y0+ys), cols [x0,x0+xs):
        // S = I[y1][x1] - I[y0-1][x1] - I[y1][x0-1] + I[y0-1][x0-1]
        float* prow = partial + (size_t)p * nrois;
        for (int n = t; n < nrois; n += 256) {
            const int4 r  = ((const int4*)rois)[n];   // ymin,xmin,ymax,xmax
            const int ys  = (r.z - r.x) / KK;
            const int xs  = (r.w - r.y) / KK;
            const int y0  = r.x + j * ys;
            const int x0  = r.y + l * xs;
            const int y1  = y0 + ys - 1;              // <= 94 < 100
            const int x1  = x0 + xs - 1;

            float S = tile[y1 * TS + x1];
            if (x0 > 0)           S -= tile[y1 * TS + (x0 - 1)];
            if (y0 > 0)           S -= tile[(y0 - 1) * TS + x1];
            if (y0 > 0 && x0 > 0) S += tile[(y0 - 1) * TS + (x0 - 1)];

            prow[n] = S;                              // coalesced 4B store
        }
    }
}

// ---------------------------------------------------------------------------
// Stage 2 (fused reduce + softmax): block handles RB=16 ROIs.
// ---------------------------------------------------------------------------
#define RB 16

__global__ __launch_bounds__(256) void reduce_softmax(
    const float* __restrict__ partial,   // [NPLANES][nrois]
    const int*   __restrict__ rois,
    int nrois,
    float*       __restrict__ out)
{
    const int dn = threadIdx.x & (RB - 1);
    const int cg = threadIdx.x / RB;     // 0..15
    const int n  = blockIdx.x * RB + dn;

    __shared__ float ch[RB][C1];

    if (n < nrois) {
        for (int c = cg; c < C1; c += 16) {
            float s = 0.f;
            const float* pc = partial + (size_t)c * nrois + n;
            #pragma unroll
            for (int jl = 0; jl < KK * KK; ++jl) {
                s += pc[(size_t)jl * C1 * nrois];
            }
            ch[dn][c] = s;
        }
    }
    __syncthreads();

    if (threadIdx.x < RB) {
        const int n2 = blockIdx.x * RB + threadIdx.x;
        if (n2 < nrois) {
            const int4 r  = ((const int4*)rois)[n2];
            const int ys  = (r.z - r.x) / KK;
            const int xs  = (r.w - r.y) / KK;
            const float inv = 1.0f / (49.0f * (float)(ys * xs));

            float v[C1];
            float m = -INFINITY;
            #pragma unroll
            for (int c = 0; c < C1; ++c) {
                v[c] = ch[threadIdx.x][c] * inv;
                m = fmaxf(m, v[c]);
            }
            float s = 0.f;
            #pragma unroll
            for (int c = 0; c < C1; ++c) { v[c] = __expf(v[c] - m); s += v[c]; }
            const float rs = 1.0f / s;
            #pragma unroll
            for (int c = 0; c < C1; ++c) out[(size_t)n2 * C1 + c] = v[c] * rs;
        }
    }
}

// ---------------------------------------------------------------------------
// Fallback (ws too small): direct rectangle summation from global.
// ---------------------------------------------------------------------------
__global__ __launch_bounds__(256) void roi_pool_direct(
    const float* __restrict__ src,
    size_t batch_off,
    const int*   __restrict__ rois,
    float*       __restrict__ out)
{
    const int n = blockIdx.x;
    const int t = threadIdx.x;

    __shared__ float chsum[C1];
    if (t < C1) chsum[t] = 0.f;
    __syncthreads();

    const int ymin = rois[4 * n + 0];
    const int xmin = rois[4 * n + 1];
    const int ymax = rois[4 * n + 2];
    const int xmax = rois[4 * n + 3];
    const int ys = (ymax - ymin) / KK;
    const int xs = (xmax - xmin) / KK;

    const float* base = src + batch_off;

    for (int idx = t; idx < NPLANES; idx += blockDim.x) {
        const int c  = idx % C1;
        const int jl = idx / C1;
        const int l  = jl % KK;
        const int j  = jl / KK;
        const int y0 = ymin + j * ys;
        const int x0 = xmin + l * xs;
        const float* plane = base + (size_t)idx * (H * W);
        float s = 0.f;
        for (int y = y0; y < y0 + ys; ++y) {
            const float* row = plane + (size_t)y * W + x0;
            for (int x = 0; x < xs; ++x) s += row[x];
        }
        atomicAdd(&chsum[c], s);
    }
    __syncthreads();

    if (t == 0) {
        const float inv = 1.0f / (49.0f * (float)(ys * xs));
        float m = -INFINITY;
        float v[C1];
        for (int c = 0; c < C1; ++c) { v[c] = chsum[c] * inv; m = fmaxf(m, v[c]); }
        float s = 0.f;
        for (int c = 0; c < C1; ++c) { v[c] = expf(v[c] - m); s += v[c]; }
        const float rs = 1.0f / s;
        for (int c = 0; c < C1; ++c) out[(size_t)n * C1 + c] = v[c] * rs;
    }
}

extern "C" void kernel_launch(void* const* d_in, const int* in_sizes, int n_in,
                              void* d_out, int out_size, void* d_ws, size_t ws_size,
                              hipStream_t stream)
{
    const float* cls  = (const float*)d_in[0];
    const int*   rois = (const int*)d_in[1];
    float*       out  = (float*)d_out;

    const int nrois = in_sizes[1] / 4;                         // 2000
    const size_t plane_elems = (size_t)NPLANES * H * W;        // 10.29 M
    const int B = (int)((size_t)in_sizes[0] / plane_elems);    // 4
    const size_t batch_off = (size_t)(B - 1) * plane_elems;

    const size_t need = (size_t)NPLANES * nrois * sizeof(float);  // ~8.2 MB
    if (ws_size >= need) {
        float* partial = (float*)d_ws;
        const int nblocks = (NPLANES + 1) / 2;                 // 515
        plane_partial<<<nblocks, 256, 0, stream>>>(cls, batch_off, rois, nrois, partial);
        reduce_softmax<<<(nrois + RB - 1) / RB, 256, 0, stream>>>(partial, rois, nrois, out);
    } else {
        roi_pool_direct<<<nrois, 256, 0, stream>>>(cls, batch_off, rois, out);
    }
}